// Round 1
// baseline (151.260 us; speedup 1.0000x reference)
//
#include <hip/hip_runtime.h>
#include <hip/hip_bf16.h>

#define BATCH 16
#define SEQ   2048
#define DIM   128
#define QBLK  64       // q rows per block (4 waves x 16)
#define KVBLK 64
#define KPAD  136      // lds_k row stride (elems): 128+8, b128-aligned (272B)
#define VPAD  68       // lds_vt row stride (elems): 64+4, 8B-aligned (136B)
#define PPAD  72       // lds_p row stride (elems): 64+8, b128-aligned (144B)
#define L2E   1.4426950408889634f

typedef __attribute__((ext_vector_type(8))) short bf16x8;
typedef __attribute__((ext_vector_type(4))) short bf16x4;
typedef __attribute__((ext_vector_type(4))) float f32x4;

__device__ __forceinline__ short f2bf(float f) {
  union { float f; unsigned u; } v; v.f = f;
  unsigned r = (v.u + 0x7FFFu + ((v.u >> 16) & 1u)) >> 16;  // RTNE
  return (short)r;
}

__global__ __launch_bounds__(256) void attn_fwd(
    const float* __restrict__ Vg, const float* __restrict__ Kg,
    const float* __restrict__ Qg, const int* __restrict__ Mg,
    float* __restrict__ Og) {
  __shared__ short lds_k[KVBLK * KPAD];    // K tile, bf16 row-major [kv][d]
  __shared__ short lds_vt[DIM * VPAD];     // V tile transposed [d][kv]
  __shared__ short lds_p[4][16 * PPAD];    // per-wave P tile [q][kv]

  const int tid = threadIdx.x;
  const int w   = tid >> 6;   // wave 0..3
  const int l   = tid & 63;
  const int g   = l >> 4;     // 16-lane group 0..3
  const int lr  = l & 15;

  const int blk = blockIdx.x;
  const int b   = blk >> 5;            // 32 q-tiles per batch
  const int q0  = (blk & 31) * QBLK;

  const float scale = 0.08838834764831845f;  // 1/sqrt(128)

  // ---- Q fragments (A-layout: row = lr, k = g*8 + kk*32 + j), pre-scaled
  bf16x8 qa[4];
  {
    const float* qbase = Qg + ((size_t)b * SEQ + (size_t)(q0 + w * 16 + lr)) * DIM + g * 8;
    #pragma unroll
    for (int kk = 0; kk < 4; ++kk) {
      const float4 x0 = *(const float4*)(qbase + kk * 32);
      const float4 x1 = *(const float4*)(qbase + kk * 32 + 4);
      bf16x8 f;
      f[0] = f2bf(x0.x * scale); f[1] = f2bf(x0.y * scale);
      f[2] = f2bf(x0.z * scale); f[3] = f2bf(x0.w * scale);
      f[4] = f2bf(x1.x * scale); f[5] = f2bf(x1.y * scale);
      f[6] = f2bf(x1.z * scale); f[7] = f2bf(x1.w * scale);
      qa[kk] = f;
    }
  }

  f32x4 acc[8];
  #pragma unroll
  for (int t = 0; t < 8; ++t) acc[t] = (f32x4){0.f, 0.f, 0.f, 0.f};
  float mrow[4] = {-1e30f, -1e30f, -1e30f, -1e30f};
  float lsum[4] = {0.f, 0.f, 0.f, 0.f};

  const float* Kb = Kg + (size_t)b * SEQ * DIM;
  const float* Vb = Vg + (size_t)b * SEQ * DIM;
  const int*   Mb = Mg + (size_t)b * SEQ * SEQ;

  for (int k0 = 0; k0 < SEQ; k0 += KVBLK) {
    __syncthreads();
    // ---- stage K tile [64][128] f32 -> bf16 row-major
    #pragma unroll
    for (int it = 0; it < 8; ++it) {
      const int idx = tid + it * 256;
      const int row = idx >> 5;
      const int c4  = idx & 31;
      const float4 x = *(const float4*)(Kb + (size_t)(k0 + row) * DIM + c4 * 4);
      bf16x4 y;
      y[0] = f2bf(x.x); y[1] = f2bf(x.y); y[2] = f2bf(x.z); y[3] = f2bf(x.w);
      *(bf16x4*)&lds_k[row * KPAD + c4 * 4] = y;
    }
    // ---- stage V tile transposed: column strips, coalesced global reads
    #pragma unroll
    for (int st = 0; st < 8; ++st) {
      const int d   = tid & 127;
      const int kv0 = ((tid >> 7) + 2 * st) * 4;
      const float x0 = Vb[(size_t)(k0 + kv0 + 0) * DIM + d];
      const float x1 = Vb[(size_t)(k0 + kv0 + 1) * DIM + d];
      const float x2 = Vb[(size_t)(k0 + kv0 + 2) * DIM + d];
      const float x3 = Vb[(size_t)(k0 + kv0 + 3) * DIM + d];
      bf16x4 y;
      y[0] = f2bf(x0); y[1] = f2bf(x1); y[2] = f2bf(x2); y[3] = f2bf(x3);
      *(bf16x4*)&lds_vt[d * VPAD + kv0] = y;
    }
    __syncthreads();

    // ---- QK^T: 4 col-subtiles of 16 kv, K-dim 128 = 4 MFMA each
    f32x4 s[4];
    #pragma unroll
    for (int sub = 0; sub < 4; ++sub) {
      f32x4 sv = (f32x4){0.f, 0.f, 0.f, 0.f};
      const int krow = sub * 16 + lr;
      #pragma unroll
      for (int kk = 0; kk < 4; ++kk) {
        bf16x8 kb = *(const bf16x8*)&lds_k[krow * KPAD + kk * 32 + g * 8];
        sv = __builtin_amdgcn_mfma_f32_16x16x32_bf16(qa[kk], kb, sv, 0, 0, 0);
      }
      s[sub] = sv;
    }
    // ---- mask: C-layout row = 4g+i, col = lr + 16*sub
    #pragma unroll
    for (int sub = 0; sub < 4; ++sub) {
      #pragma unroll
      for (int i = 0; i < 4; ++i) {
        const int qrow = q0 + w * 16 + 4 * g + i;
        const int mv = Mb[(size_t)qrow * SEQ + (size_t)(k0 + sub * 16 + lr)];
        if (mv == -100) s[sub][i] = -1e30f;
      }
    }
    // ---- online softmax (rows 4g+i; reduce across the 16-lane group)
    float alpha[4];
    #pragma unroll
    for (int i = 0; i < 4; ++i) {
      float tm = fmaxf(fmaxf(s[0][i], s[1][i]), fmaxf(s[2][i], s[3][i]));
      #pragma unroll
      for (int dlt = 1; dlt < 16; dlt <<= 1)
        tm = fmaxf(tm, __shfl_xor(tm, dlt, 16));
      const float mnew = fmaxf(mrow[i], tm);
      alpha[i] = __builtin_amdgcn_exp2f((mrow[i] - mnew) * L2E);
      mrow[i] = mnew;
      lsum[i] *= alpha[i];
    }
    #pragma unroll
    for (int t = 0; t < 8; ++t) {
      #pragma unroll
      for (int i = 0; i < 4; ++i) acc[t][i] *= alpha[i];
    }
    // ---- P = exp(s - m), per-lane partial lsum, write P to LDS (C->A layout)
    #pragma unroll
    for (int sub = 0; sub < 4; ++sub) {
      #pragma unroll
      for (int i = 0; i < 4; ++i) {
        const float p = __builtin_amdgcn_exp2f((s[sub][i] - mrow[i]) * L2E);
        lsum[i] += p;
        lds_p[w][(4 * g + i) * PPAD + sub * 16 + lr] = f2bf(p);
      }
    }
    // ---- PV: A = P (from lds_p, A-layout), B = V (from lds_vt, contiguous kv)
    bf16x8 pa[2];
    #pragma unroll
    for (int kk = 0; kk < 2; ++kk)
      pa[kk] = *(const bf16x8*)&lds_p[w][lr * PPAD + kk * 32 + g * 8];
    #pragma unroll
    for (int t = 0; t < 8; ++t) {
      #pragma unroll
      for (int kk = 0; kk < 2; ++kk) {
        const int voff = (16 * t + lr) * VPAD + kk * 32 + g * 8;
        bf16x4 v0 = *(const bf16x4*)&lds_vt[voff];
        bf16x4 v1 = *(const bf16x4*)&lds_vt[voff + 4];
        bf16x8 vb = __builtin_shufflevector(v0, v1, 0, 1, 2, 3, 4, 5, 6, 7);
        acc[t] = __builtin_amdgcn_mfma_f32_16x16x32_bf16(pa[kk], vb, acc[t], 0, 0, 0);
      }
    }
  }

  // ---- finalize: reduce lsum across 16-lane group, normalize, store
  float rden[4];
  #pragma unroll
  for (int i = 0; i < 4; ++i) {
    float sm = lsum[i];
    #pragma unroll
    for (int dlt = 1; dlt < 16; dlt <<= 1) sm += __shfl_xor(sm, dlt, 16);
    rden[i] = 1.f / sm;
  }
  float* ob = Og + ((size_t)b * SEQ + (size_t)(q0 + w * 16)) * DIM;
  #pragma unroll
  for (int t = 0; t < 8; ++t) {
    #pragma unroll
    for (int i = 0; i < 4; ++i)
      ob[(4 * g + i) * DIM + 16 * t + lr] = acc[t][i] * rden[i];
  }
}

extern "C" void kernel_launch(void* const* d_in, const int* in_sizes, int n_in,
                              void* d_out, int out_size, void* d_ws, size_t ws_size,
                              hipStream_t stream) {
  (void)in_sizes; (void)n_in; (void)d_ws; (void)ws_size; (void)out_size;
  const float* Vg = (const float*)d_in[0];
  const float* Kg = (const float*)d_in[1];
  const float* Qg = (const float*)d_in[2];
  const int*   Mg = (const int*)d_in[3];
  float* Og = (float*)d_out;
  dim3 grid(BATCH * (SEQ / QBLK));
  attn_fwd<<<grid, 256, 0, stream>>>(Vg, Kg, Qg, Mg, Og);
}

// Round 2
// 128.729 us; speedup vs baseline: 1.1750x; 1.1750x over previous
//
#include <hip/hip_runtime.h>
#include <hip/hip_bf16.h>

#define BATCH 16
#define SEQ   2048
#define DIM   128
#define QBLK  64       // q rows per block (4 waves x 16)
#define KVBLK 64
#define NT    (SEQ / KVBLK)
#define KPAD  136      // lds_k row stride (elems)
#define VPAD  68       // lds_vt row stride (elems)
#define PPAD  72       // lds_p row stride (elems)
#define L2E   1.4426950408889634f
#define THR   8.0f     // defer-max rescale threshold (T13)

typedef __attribute__((ext_vector_type(8))) short bf16x8;
typedef __attribute__((ext_vector_type(4))) short bf16x4;
typedef __attribute__((ext_vector_type(4))) float f32x4;

__device__ __forceinline__ short f2bf(float f) {
  union { float f; unsigned u; } v; v.f = f;
  unsigned r = (v.u + 0x7FFFu + ((v.u >> 16) & 1u)) >> 16;  // RTNE
  return (short)r;
}

// Issue next tile's K+V global loads into registers (T14 issue-early).
__device__ __forceinline__ void issue_kv(const float* __restrict__ Kb,
                                         const float* __restrict__ Vb,
                                         int k0, int tid,
                                         float4 (&kreg)[8], float (&vreg)[32]) {
  #pragma unroll
  for (int it = 0; it < 8; ++it) {
    const int idx = tid + it * 256;
    kreg[it] = *(const float4*)(Kb + (size_t)(k0 + (idx >> 5)) * DIM + (idx & 31) * 4);
  }
  const int d = tid & 127;
  #pragma unroll
  for (int st = 0; st < 8; ++st) {
    const int kv0 = ((tid >> 7) + 2 * st) * 4;
    #pragma unroll
    for (int j = 0; j < 4; ++j)
      vreg[st * 4 + j] = Vb[(size_t)(k0 + kv0 + j) * DIM + d];
  }
}

// Issue next tile's mask loads into registers.
__device__ __forceinline__ void issue_m(const int* const (&Mrow)[4], int k0,
                                        int (&mreg)[16]) {
  #pragma unroll
  for (int sub = 0; sub < 4; ++sub)
    #pragma unroll
    for (int i = 0; i < 4; ++i)
      mreg[sub * 4 + i] = Mrow[i][k0 + sub * 16];
}

__global__ __launch_bounds__(256, 2) void attn_fwd(
    const float* __restrict__ Vg, const float* __restrict__ Kg,
    const float* __restrict__ Qg, const int* __restrict__ Mg,
    float* __restrict__ Og) {
  __shared__ short lds_k[KVBLK * KPAD];    // K tile, bf16 row-major [kv][d]
  __shared__ short lds_vt[DIM * VPAD];     // V tile transposed [d][kv]
  __shared__ short lds_p[4][16 * PPAD];    // per-wave P tile [q][kv]

  const int tid = threadIdx.x;
  const int w   = tid >> 6;
  const int l   = tid & 63;
  const int g   = l >> 4;
  const int lr  = l & 15;

  const int blk = blockIdx.x;
  const int b   = blk >> 5;
  const int q0  = (blk & 31) * QBLK;

  const float scale = 0.08838834764831845f;  // 1/sqrt(128)

  // ---- Q fragments (A-layout: row = lr, k = g*8 + kk*32 + j), pre-scaled
  bf16x8 qa[4];
  {
    const float* qbase = Qg + ((size_t)b * SEQ + (size_t)(q0 + w * 16 + lr)) * DIM + g * 8;
    #pragma unroll
    for (int kk = 0; kk < 4; ++kk) {
      const float4 x0 = *(const float4*)(qbase + kk * 32);
      const float4 x1 = *(const float4*)(qbase + kk * 32 + 4);
      bf16x8 f;
      f[0] = f2bf(x0.x * scale); f[1] = f2bf(x0.y * scale);
      f[2] = f2bf(x0.z * scale); f[3] = f2bf(x0.w * scale);
      f[4] = f2bf(x1.x * scale); f[5] = f2bf(x1.y * scale);
      f[6] = f2bf(x1.z * scale); f[7] = f2bf(x1.w * scale);
      qa[kk] = f;
    }
  }

  f32x4 acc[8];
  #pragma unroll
  for (int t = 0; t < 8; ++t) acc[t] = (f32x4){0.f, 0.f, 0.f, 0.f};
  float mrow[4] = {-1e30f, -1e30f, -1e30f, -1e30f};
  float lsum[4] = {0.f, 0.f, 0.f, 0.f};

  const float* Kb = Kg + (size_t)b * SEQ * DIM;
  const float* Vb = Vg + (size_t)b * SEQ * DIM;
  const int*   Mb = Mg + (size_t)b * SEQ * SEQ;
  const int* const Mrow[4] = {
    Mb + (size_t)(q0 + w * 16 + 4 * g + 0) * SEQ + lr,
    Mb + (size_t)(q0 + w * 16 + 4 * g + 1) * SEQ + lr,
    Mb + (size_t)(q0 + w * 16 + 4 * g + 2) * SEQ + lr,
    Mb + (size_t)(q0 + w * 16 + 4 * g + 3) * SEQ + lr };

  // ---- prefetch registers
  float4 kreg[8];
  float  vreg[32];
  int    mreg[16];

  issue_kv(Kb, Vb, 0, tid, kreg, vreg);
  issue_m(Mrow, 0, mreg);

  for (int t = 0; t < NT; ++t) {
    const int k0 = t * KVBLK;
    __syncthreads();   // prev tile's LDS reads done; vmcnt drain = consume point

    // ---- write prefetched K tile to LDS (f32 regs -> bf16)
    #pragma unroll
    for (int it = 0; it < 8; ++it) {
      const int idx = tid + it * 256;
      const int row = idx >> 5;
      const int c4  = idx & 31;
      const float4 x = kreg[it];
      bf16x4 y;
      y[0] = f2bf(x.x); y[1] = f2bf(x.y); y[2] = f2bf(x.z); y[3] = f2bf(x.w);
      *(bf16x4*)&lds_k[row * KPAD + c4 * 4] = y;
    }
    // ---- write prefetched V tile (transposed) to LDS
    {
      const int d = tid & 127;
      #pragma unroll
      for (int st = 0; st < 8; ++st) {
        const int kv0 = ((tid >> 7) + 2 * st) * 4;
        bf16x4 y;
        y[0] = f2bf(vreg[st * 4 + 0]); y[1] = f2bf(vreg[st * 4 + 1]);
        y[2] = f2bf(vreg[st * 4 + 2]); y[3] = f2bf(vreg[st * 4 + 3]);
        *(bf16x4*)&lds_vt[d * VPAD + kv0] = y;
      }
    }
    __syncthreads();

    // ---- issue next tile's K/V loads: latency hides under compute (T14)
    if (t + 1 < NT) issue_kv(Kb, Vb, k0 + KVBLK, tid, kreg, vreg);

    // ---- QK^T
    f32x4 s[4];
    #pragma unroll
    for (int sub = 0; sub < 4; ++sub) {
      f32x4 sv = (f32x4){0.f, 0.f, 0.f, 0.f};
      const int krow = sub * 16 + lr;
      #pragma unroll
      for (int kk = 0; kk < 4; ++kk) {
        bf16x8 kb = *(const bf16x8*)&lds_k[krow * KPAD + kk * 32 + g * 8];
        sv = __builtin_amdgcn_mfma_f32_16x16x32_bf16(qa[kk], kb, sv, 0, 0, 0);
      }
      s[sub] = sv;
    }

    // ---- apply prefetched mask (C-layout row = 4g+i, col = lr + 16*sub)
    #pragma unroll
    for (int sub = 0; sub < 4; ++sub) {
      #pragma unroll
      for (int i = 0; i < 4; ++i) {
        if (mreg[sub * 4 + i] == -100) s[sub][i] = -1e30f;
      }
    }
    if (t + 1 < NT) issue_m(Mrow, k0 + KVBLK, mreg);

    // ---- online softmax with defer-max (T13): decide on m_old, then update
    float tmax[4];
    bool chg = false;
    #pragma unroll
    for (int i = 0; i < 4; ++i) {
      float tm = fmaxf(fmaxf(s[0][i], s[1][i]), fmaxf(s[2][i], s[3][i]));
      #pragma unroll
      for (int dlt = 1; dlt < 16; dlt <<= 1)
        tm = fmaxf(tm, __shfl_xor(tm, dlt, 16));
      tmax[i] = tm;
      chg = chg || (tm > mrow[i] + THR);
    }
    if (__any(chg)) {   // wave-uniform; skipped ~31/32 tiles after warm-up
      #pragma unroll
      for (int i = 0; i < 4; ++i) {
        const float mnew = fmaxf(mrow[i], tmax[i]);
        const float alpha = __builtin_amdgcn_exp2f((mrow[i] - mnew) * L2E);
        mrow[i] = mnew;
        lsum[i] *= alpha;
        #pragma unroll
        for (int t8 = 0; t8 < 8; ++t8) acc[t8][i] *= alpha;
      }
    }

    // ---- P = exp2((s - m)*L2E)  (bounded by 2^(THR*L2E) ~ 2900, bf16-safe)
    #pragma unroll
    for (int sub = 0; sub < 4; ++sub) {
      #pragma unroll
      for (int i = 0; i < 4; ++i) {
        const float p = __builtin_amdgcn_exp2f((s[sub][i] - mrow[i]) * L2E);
        lsum[i] += p;
        lds_p[w][(4 * g + i) * PPAD + sub * 16 + lr] = f2bf(p);
      }
    }

    // ---- PV
    bf16x8 pa[2];
    #pragma unroll
    for (int kk = 0; kk < 2; ++kk)
      pa[kk] = *(const bf16x8*)&lds_p[w][lr * PPAD + kk * 32 + g * 8];
    #pragma unroll
    for (int t8 = 0; t8 < 8; ++t8) {
      #pragma unroll
      for (int kk = 0; kk < 2; ++kk) {
        const int voff = (16 * t8 + lr) * VPAD + kk * 32 + g * 8;
        bf16x4 v0 = *(const bf16x4*)&lds_vt[voff];
        bf16x4 v1 = *(const bf16x4*)&lds_vt[voff + 4];
        bf16x8 vb = __builtin_shufflevector(v0, v1, 0, 1, 2, 3, 4, 5, 6, 7);
        acc[t8] = __builtin_amdgcn_mfma_f32_16x16x32_bf16(pa[kk], vb, acc[t8], 0, 0, 0);
      }
    }
  }

  // ---- finalize
  float rden[4];
  #pragma unroll
  for (int i = 0; i < 4; ++i) {
    float sm = lsum[i];
    #pragma unroll
    for (int dlt = 1; dlt < 16; dlt <<= 1) sm += __shfl_xor(sm, dlt, 16);
    rden[i] = 1.f / sm;
  }
  float* ob = Og + ((size_t)b * SEQ + (size_t)(q0 + w * 16)) * DIM;
  #pragma unroll
  for (int t8 = 0; t8 < 8; ++t8) {
    #pragma unroll
    for (int i = 0; i < 4; ++i)
      ob[(4 * g + i) * DIM + 16 * t8 + lr] = acc[t8][i] * rden[i];
  }
}

extern "C" void kernel_launch(void* const* d_in, const int* in_sizes, int n_in,
                              void* d_out, int out_size, void* d_ws, size_t ws_size,
                              hipStream_t stream) {
  (void)in_sizes; (void)n_in; (void)d_ws; (void)ws_size; (void)out_size;
  const float* Vg = (const float*)d_in[0];
  const float* Kg = (const float*)d_in[1];
  const float* Qg = (const float*)d_in[2];
  const int*   Mg = (const int*)d_in[3];
  float* Og = (float*)d_out;
  dim3 grid(BATCH * (SEQ / QBLK));
  attn_fwd<<<grid, 256, 0, stream>>>(Vg, Kg, Qg, Mg, Og);
}